// Round 6
// baseline (333.733 us; speedup 1.0000x reference)
//
#include <hip/hip_runtime.h>
#include <stdint.h>

// S3FD anchor assignment — fused single-pass + per-GT-block reduction.
// d_in[0]: anchor [N,4] f32, d_in[1]: gt [M,4] f32. d_out: assign [N] int32.
//
// Round 5 post-mortem: k_fused 150 us (VALUBusy 83%, Occ 33%, grid-limited at
// slice=512) and ~117 us hiding in the k_mid/k_finalize tail (latency-bound,
// 128 then 1 block). Round 6: slice=256 (1954 blocks ~7.6/CU), LDS cut to
// ~11 KB (4-round epilogue merge), pair-max INS3 (insert max of the two
// anchors' keys; min only when it also beats t2 — rare), and the tail becomes
// k_reduce (M=200 blocks, butterfly) + k_claims (1 tiny block).
//
// Key encoding (exact jax semantics), per-GT top-3:
//   key = (iou_bits << 32) | ~anchor_idx    (stable top_k: higher iou, then
//                                            lower anchor index wins)

#define POS_THRESH 0.5f
#define NEG_THRESH 0.3f
#define CLAIM_THRESH 0.1f

constexpr int MPAD = 256;    // padded GT count (M = 200)

#define INS3(t0, t1, t2, k) do {                                  \
    if ((k) > (t2)) {                                             \
        if ((k) > (t0))      { t2 = t1; t1 = t0; t0 = (k); }      \
        else if ((k) > (t1)) { t2 = t1; t1 = (k); }               \
        else                 { t2 = (k); }                        \
    } } while (0)

__device__ __forceinline__ unsigned long long shfl_xor_u64(unsigned long long x,
                                                           int mask) {
    int lo = __shfl_xor((int)(unsigned)x, mask, 64);
    int hi = __shfl_xor((int)(unsigned)(x >> 32), mask, 64);
    return ((unsigned long long)(unsigned)hi << 32) | (unsigned)lo;
}

// ---------------------------------------------------------------------------
// Fused kernel: base assignment + per-(block,GT) top-3 partials.
// grid = ceil(N/slice) blocks x 256 threads; slice is a multiple of 256.
// Lane l owns GTs {l, l+64, l+128, l+192} entirely in named-scalar registers.
// ---------------------------------------------------------------------------
__global__ void __launch_bounds__(256) k_fused(
    const float4* __restrict__ anchor, const float4* __restrict__ gt,
    int* __restrict__ out, unsigned long long* __restrict__ partial,
    int N, int M, int slice)
{
    __shared__ float4 s_abox[256];                       // 4 KB
    __shared__ float  s_aarea[256];                      // 1 KB
    __shared__ unsigned long long s_red[4][64][3];       // 6 KB

    const int tid  = threadIdx.x;
    const int lane = tid & 63;
    const int w    = tid >> 6;

#define GTDECL(r)                                                  \
    float gx1_##r, gy1_##r, gx2_##r, gy2_##r, ga_##r;             \
    unsigned long long t0_##r = 0, t1_##r = 0, t2_##r = 0;
    GTDECL(0) GTDECL(1) GTDECL(2) GTDECL(3)

#define GTLOAD(r) {                                                \
    int m = lane + (r) * 64;                                       \
    float4 g = (m < M) ? gt[m] : make_float4(0.f, 0.f, 0.f, 0.f);  \
    gx1_##r = g.x; gy1_##r = g.y; gx2_##r = g.z; gy2_##r = g.w;    \
    ga_##r = (g.z - g.x) * (g.w - g.y); }
    GTLOAD(0) GTLOAD(1) GTLOAD(2) GTLOAD(3)

    const int base = blockIdx.x * slice;
    const int rem  = N - base;
    const int nt   = ((rem < slice ? rem : slice) + 255) >> 8;

    for (int tile = 0; tile < nt; ++tile) {
        const int tb = base + (tile << 8);
        {
            int gi = tb + tid;
            float4 ab = (gi < N) ? anchor[gi]
                                 : make_float4(0.f, 0.f, 0.f, 0.f);
            __syncthreads();           // previous tile's readers done
            s_abox[tid]  = ab;
            s_aarea[tid] = (ab.z - ab.x) * (ab.w - ab.y);
            __syncthreads();
        }

        const int jbase = tb + (w << 6);   // this wave's 64 anchors
        int myassign = -2;

        // two anchors per iteration: independent reductions -> ILP
        for (int jj = 0; jj < 64; jj += 2) {
            const int j = (w << 6) + jj;
            float4 aA     = s_abox[j];
            float4 aB     = s_abox[j + 1];
            float  areaA  = s_aarea[j];
            float  areaB  = s_aarea[j + 1];
            unsigned naiA = ~(unsigned)(jbase + jj);
            unsigned naiB = ~(unsigned)(jbase + jj + 1);
            unsigned ibA_0, ibA_1, ibA_2, ibA_3;
            unsigned ibB_0, ibB_1, ibB_2, ibB_3;

            // pair-max insert: common path pays ONE u64 max + ONE INS3;
            // the smaller key is inserted only when it also beats t2 (rare).
#define PAIR2(r) {                                                 \
            float ltxA = fmaxf(aA.x, gx1_##r);                     \
            float ltyA = fmaxf(aA.y, gy1_##r);                     \
            float rbxA = fminf(aA.z, gx2_##r);                     \
            float rbyA = fminf(aA.w, gy2_##r);                     \
            float wA   = fmaxf(rbxA - ltxA, 0.0f);                 \
            float hA   = fmaxf(rbyA - ltyA, 0.0f);                 \
            float interA = wA * hA;                                \
            float iouA = 0.0f;                                     \
            if (interA > 0.0f)                                     \
                iouA = interA / ((areaA + ga_##r) - interA);       \
            ibA_##r = __float_as_uint(iouA);                       \
            float ltxB = fmaxf(aB.x, gx1_##r);                     \
            float ltyB = fmaxf(aB.y, gy1_##r);                     \
            float rbxB = fminf(aB.z, gx2_##r);                     \
            float rbyB = fminf(aB.w, gy2_##r);                     \
            float wB   = fmaxf(rbxB - ltxB, 0.0f);                 \
            float hB   = fmaxf(rbyB - ltyB, 0.0f);                 \
            float interB = wB * hB;                                \
            float iouB = 0.0f;                                     \
            if (interB > 0.0f)                                     \
                iouB = interB / ((areaB + ga_##r) - interB);       \
            ibB_##r = __float_as_uint(iouB);                       \
            unsigned long long ktA =                               \
                ((unsigned long long)ibA_##r << 32) | naiA;        \
            unsigned long long ktB =                               \
                ((unsigned long long)ibB_##r << 32) | naiB;        \
            unsigned long long kmx = (ktA > ktB) ? ktA : ktB;      \
            unsigned long long kmn = (ktA > ktB) ? ktB : ktA;      \
            if (kmn > t2_##r) {                                    \
                INS3(t0_##r, t1_##r, t2_##r, kmx);                 \
                INS3(t0_##r, t1_##r, t2_##r, kmn);                 \
            } else {                                               \
                INS3(t0_##r, t1_##r, t2_##r, kmx);                 \
            } }
            PAIR2(0) PAIR2(1) PAIR2(2) PAIR2(3)

            // per-lane max iou bits over 4 slots, then u32 wave butterfly
            unsigned mxA = max(max(ibA_0, ibA_1), max(ibA_2, ibA_3));
            unsigned mxB = max(max(ibB_0, ibB_1), max(ibB_2, ibB_3));
            for (int off = 1; off < 64; off <<= 1) {
                unsigned oA = __shfl_xor(mxA, off, 64);
                unsigned oB = __shfl_xor(mxB, off, 64);
                mxA = (oA > mxA) ? oA : mxA;
                mxB = (oB > mxB) ? oB : mxB;
            }

            // argmax index: smallest m = smallest slot r, then smallest lane
            unsigned long long bA0 = __ballot(ibA_0 == mxA);
            unsigned long long bA1 = __ballot(ibA_1 == mxA);
            unsigned long long bA2 = __ballot(ibA_2 == mxA);
            unsigned long long bA3 = __ballot(ibA_3 == mxA);
            int mA;
            if      (bA0) mA =       __builtin_ctzll(bA0);
            else if (bA1) mA =  64 + __builtin_ctzll(bA1);
            else if (bA2) mA = 128 + __builtin_ctzll(bA2);
            else          mA = 192 + __builtin_ctzll(bA3);

            unsigned long long bB0 = __ballot(ibB_0 == mxB);
            unsigned long long bB1 = __ballot(ibB_1 == mxB);
            unsigned long long bB2 = __ballot(ibB_2 == mxB);
            unsigned long long bB3 = __ballot(ibB_3 == mxB);
            int mB;
            if      (bB0) mB =       __builtin_ctzll(bB0);
            else if (bB1) mB =  64 + __builtin_ctzll(bB1);
            else if (bB2) mB = 128 + __builtin_ctzll(bB2);
            else          mB = 192 + __builtin_ctzll(bB3);

            // thresholds as unsigned bit-compares (iou >= 0 -> monotone)
            int vA = -2;
            if (mxA < __float_as_uint(NEG_THRESH)) vA = -1;
            if (mxA > __float_as_uint(POS_THRESH)) vA = mA;
            int vB = -2;
            if (mxB < __float_as_uint(NEG_THRESH)) vB = -1;
            if (mxB > __float_as_uint(POS_THRESH)) vB = mB;
            if (jj == lane)     myassign = vA;
            if (jj + 1 == lane) myassign = vB;
        }

        int gout = jbase + lane;
        if (gout < N) out[gout] = myassign;
    }

    // ---- merge 4 waves' per-GT top-3, one slot r at a time (6 KB LDS) ---
    const int blk = blockIdx.x;
#define EPI(r) {                                                   \
    __syncthreads();                                               \
    s_red[w][lane][0] = t0_##r;                                    \
    s_red[w][lane][1] = t1_##r;                                    \
    s_red[w][lane][2] = t2_##r;                                    \
    __syncthreads();                                               \
    if (tid < 64) {                                                \
        int m = tid + (r) * 64;                                    \
        if (m < M) {                                               \
            unsigned long long r0 = 0, r1 = 0, r2 = 0;             \
            for (int wv = 0; wv < 4; ++wv) {                       \
                INS3(r0, r1, r2, s_red[wv][tid][0]);               \
                INS3(r0, r1, r2, s_red[wv][tid][1]);               \
                INS3(r0, r1, r2, s_red[wv][tid][2]);               \
            }                                                      \
            partial[((size_t)blk * 3 + 0) * M + m] = r0;           \
            partial[((size_t)blk * 3 + 1) * M + m] = r1;           \
            partial[((size_t)blk * 3 + 2) * M + m] = r2;           \
        }                                                          \
    } }
    EPI(0) EPI(1) EPI(2) EPI(3)
}

// ---------------------------------------------------------------------------
// Per-GT reduce: grid = M blocks; block m merges all chunk partials for GT m.
// ---------------------------------------------------------------------------
__global__ void __launch_bounds__(256) k_reduce(
    const unsigned long long* __restrict__ partial,
    unsigned long long* __restrict__ final3, int M, int nblk)
{
    const int m    = blockIdx.x;
    const int tid  = threadIdx.x;
    const int lane = tid & 63;
    const int w    = tid >> 6;

    unsigned long long r0 = 0, r1 = 0, r2 = 0;
    for (int c = tid; c < nblk; c += 256) {
        const unsigned long long* p = partial + (size_t)c * 3 * M + m;
        INS3(r0, r1, r2, p[0 * M]);
        INS3(r0, r1, r2, p[1 * M]);
        INS3(r0, r1, r2, p[2 * M]);
    }

    for (int off = 1; off < 64; off <<= 1) {
        unsigned long long o0 = shfl_xor_u64(r0, off);
        unsigned long long o1 = shfl_xor_u64(r1, off);
        unsigned long long o2 = shfl_xor_u64(r2, off);
        INS3(r0, r1, r2, o0);
        INS3(r0, r1, r2, o1);
        INS3(r0, r1, r2, o2);
    }

    __shared__ unsigned long long s_red[4][3];
    if (lane == 0) {
        s_red[w][0] = r0; s_red[w][1] = r1; s_red[w][2] = r2;
    }
    __syncthreads();
    if (tid == 0) {
        unsigned long long q0 = 0, q1 = 0, q2 = 0;
        for (int wv = 0; wv < 4; ++wv) {
            INS3(q0, q1, q2, s_red[wv][0]);
            INS3(q0, q1, q2, s_red[wv][1]);
            INS3(q0, q1, q2, s_red[wv][2]);
        }
        final3[m * 3 + 0] = q0;
        final3[m * 3 + 1] = q1;
        final3[m * 3 + 2] = q2;
    }
}

// ---------------------------------------------------------------------------
// Claims: read final top-3 per GT, apply forced-claim scatter-max.
// Single small block. "Later gt overwrites earlier" == max claiming gt wins.
// ---------------------------------------------------------------------------
__global__ void __launch_bounds__(256) k_claims(
    const unsigned long long* __restrict__ final3, int* __restrict__ out, int M)
{
    __shared__ int s_a[3 * MPAD];
    __shared__ int s_cv[3 * MPAD];
    const int tid = threadIdx.x;

    if (tid < M) {
        unsigned long long q0 = final3[tid * 3 + 0];
        unsigned long long q1 = final3[tid * 3 + 1];
        unsigned long long q2 = final3[tid * 3 + 2];
        float v0 = __uint_as_float((unsigned)(q0 >> 32));
        float v1 = __uint_as_float((unsigned)(q1 >> 32));
        float v2 = __uint_as_float((unsigned)(q2 >> 32));
        int a0 = (int)(~(unsigned)q0);
        int a1 = (int)(~(unsigned)q1);
        int a2 = (int)(~(unsigned)q2);

        int npos = (v0 > POS_THRESH) + (v1 > POS_THRESH) + (v2 > POS_THRESH);
        bool low = npos < 3;

        s_a[tid * 3 + 0] = a0;
        s_a[tid * 3 + 1] = a1;
        s_a[tid * 3 + 2] = a2;
        s_cv[tid * 3 + 0] = tid;                                   // k==0 forced
        s_cv[tid * 3 + 1] = (low && v1 > CLAIM_THRESH) ? tid : -1;
        s_cv[tid * 3 + 2] = (low && v2 > CLAIM_THRESH) ? tid : -1;
    }
    __syncthreads();

    // scatter-max: contested anchor -> highest claiming gt index wins
    const int tote = 3 * M;
    for (int e = tid; e < tote; e += 256) {
        int cv = s_cv[e];
        if (cv < 0) continue;
        int a = s_a[e];
        bool win = true;
        for (int f = 0; f < tote; ++f) {
            if (s_cv[f] > cv && s_a[f] == a) { win = false; break; }
        }
        if (win) out[a] = cv;
    }
}

// ---------------------------------------------------------------------------
extern "C" void kernel_launch(void* const* d_in, const int* in_sizes, int n_in,
                              void* d_out, int out_size, void* d_ws, size_t ws_size,
                              hipStream_t stream) {
    const float4* anchor = (const float4*)d_in[0];
    const float4* gt     = (const float4*)d_in[1];
    int N = in_sizes[0] / 4;
    int M = in_sizes[1] / 4;
    int* out = (int*)d_out;

    // slice = anchors per block (multiple of 256); fall back to bigger slices
    // if the partial buffer would overflow the workspace.
    int slice = 256;
    int nblk  = (N + slice - 1) / slice;
    while ((size_t)(nblk * 3 + 3) * M * sizeof(unsigned long long) > ws_size &&
           slice < (1 << 24)) {
        slice <<= 1;
        nblk = (N + slice - 1) / slice;
    }

    unsigned long long* partial = (unsigned long long*)d_ws;
    unsigned long long* final3  = partial + (size_t)nblk * 3 * M;

    k_fused<<<nblk, 256, 0, stream>>>(anchor, gt, out, partial, N, M, slice);
    k_reduce<<<M, 256, 0, stream>>>(partial, final3, M, nblk);
    k_claims<<<1, 256, 0, stream>>>(final3, out, M);
}

// Round 7
// 198.387 us; speedup vs baseline: 1.6822x; 1.6822x over previous
//
#include <hip/hip_runtime.h>
#include <stdint.h>

// S3FD anchor assignment — fused single-pass + coalesced 3-stage reduction.
// d_in[0]: anchor [N,4] f32, d_in[1]: gt [M,4] f32. d_out: assign [N] int32.
//
// Round 6 post-mortem: k_claims was 181 us at VALUBusy 0.013% — the winner
// check's `break` made a serial dependent ds_read chain (~1800 x 120cy).
// Round 7: claims loop is break-free over packed u64 keys (independent loads,
// pipelineable); reduction is k_mid (coalesced, lanes-on-m, 1954->256) +
// k_gt (per-GT butterfly). k_fused unchanged from round 6 (~110 us).
//
// Key encoding (exact jax semantics), per-GT top-3:
//   key = (iou_bits << 32) | ~anchor_idx    (stable top_k: higher iou, then
//                                            lower anchor index wins)

#define POS_THRESH 0.5f
#define NEG_THRESH 0.3f
#define CLAIM_THRESH 0.1f

constexpr int MPAD = 256;    // padded GT count (M = 200)
constexpr int G2   = 256;    // mid-stage block count

#define INS3(t0, t1, t2, k) do {                                  \
    if ((k) > (t2)) {                                             \
        if ((k) > (t0))      { t2 = t1; t1 = t0; t0 = (k); }      \
        else if ((k) > (t1)) { t2 = t1; t1 = (k); }               \
        else                 { t2 = (k); }                        \
    } } while (0)

__device__ __forceinline__ unsigned long long shfl_xor_u64(unsigned long long x,
                                                           int mask) {
    int lo = __shfl_xor((int)(unsigned)x, mask, 64);
    int hi = __shfl_xor((int)(unsigned)(x >> 32), mask, 64);
    return ((unsigned long long)(unsigned)hi << 32) | (unsigned)lo;
}

// ---------------------------------------------------------------------------
// Fused kernel: base assignment + per-(block,GT) top-3 partials.
// grid = ceil(N/slice) blocks x 256 threads; slice is a multiple of 256.
// Lane l owns GTs {l, l+64, l+128, l+192} entirely in named-scalar registers.
// ---------------------------------------------------------------------------
__global__ void __launch_bounds__(256) k_fused(
    const float4* __restrict__ anchor, const float4* __restrict__ gt,
    int* __restrict__ out, unsigned long long* __restrict__ partial,
    int N, int M, int slice)
{
    __shared__ float4 s_abox[256];                       // 4 KB
    __shared__ float  s_aarea[256];                      // 1 KB
    __shared__ unsigned long long s_red[4][64][3];       // 6 KB

    const int tid  = threadIdx.x;
    const int lane = tid & 63;
    const int w    = tid >> 6;

#define GTDECL(r)                                                  \
    float gx1_##r, gy1_##r, gx2_##r, gy2_##r, ga_##r;             \
    unsigned long long t0_##r = 0, t1_##r = 0, t2_##r = 0;
    GTDECL(0) GTDECL(1) GTDECL(2) GTDECL(3)

#define GTLOAD(r) {                                                \
    int m = lane + (r) * 64;                                       \
    float4 g = (m < M) ? gt[m] : make_float4(0.f, 0.f, 0.f, 0.f);  \
    gx1_##r = g.x; gy1_##r = g.y; gx2_##r = g.z; gy2_##r = g.w;    \
    ga_##r = (g.z - g.x) * (g.w - g.y); }
    GTLOAD(0) GTLOAD(1) GTLOAD(2) GTLOAD(3)

    const int base = blockIdx.x * slice;
    const int rem  = N - base;
    const int nt   = ((rem < slice ? rem : slice) + 255) >> 8;

    for (int tile = 0; tile < nt; ++tile) {
        const int tb = base + (tile << 8);
        {
            int gi = tb + tid;
            float4 ab = (gi < N) ? anchor[gi]
                                 : make_float4(0.f, 0.f, 0.f, 0.f);
            __syncthreads();           // previous tile's readers done
            s_abox[tid]  = ab;
            s_aarea[tid] = (ab.z - ab.x) * (ab.w - ab.y);
            __syncthreads();
        }

        const int jbase = tb + (w << 6);   // this wave's 64 anchors
        int myassign = -2;

        // two anchors per iteration: independent reductions -> ILP
        for (int jj = 0; jj < 64; jj += 2) {
            const int j = (w << 6) + jj;
            float4 aA     = s_abox[j];
            float4 aB     = s_abox[j + 1];
            float  areaA  = s_aarea[j];
            float  areaB  = s_aarea[j + 1];
            unsigned naiA = ~(unsigned)(jbase + jj);
            unsigned naiB = ~(unsigned)(jbase + jj + 1);
            unsigned ibA_0, ibA_1, ibA_2, ibA_3;
            unsigned ibB_0, ibB_1, ibB_2, ibB_3;

            // pair-max insert: common path pays ONE u64 max + ONE INS3;
            // the smaller key is inserted only when it also beats t2 (rare).
#define PAIR2(r) {                                                 \
            float ltxA = fmaxf(aA.x, gx1_##r);                     \
            float ltyA = fmaxf(aA.y, gy1_##r);                     \
            float rbxA = fminf(aA.z, gx2_##r);                     \
            float rbyA = fminf(aA.w, gy2_##r);                     \
            float wA   = fmaxf(rbxA - ltxA, 0.0f);                 \
            float hA   = fmaxf(rbyA - ltyA, 0.0f);                 \
            float interA = wA * hA;                                \
            float iouA = 0.0f;                                     \
            if (interA > 0.0f)                                     \
                iouA = interA / ((areaA + ga_##r) - interA);       \
            ibA_##r = __float_as_uint(iouA);                       \
            float ltxB = fmaxf(aB.x, gx1_##r);                     \
            float ltyB = fmaxf(aB.y, gy1_##r);                     \
            float rbxB = fminf(aB.z, gx2_##r);                     \
            float rbyB = fminf(aB.w, gy2_##r);                     \
            float wB   = fmaxf(rbxB - ltxB, 0.0f);                 \
            float hB   = fmaxf(rbyB - ltyB, 0.0f);                 \
            float interB = wB * hB;                                \
            float iouB = 0.0f;                                     \
            if (interB > 0.0f)                                     \
                iouB = interB / ((areaB + ga_##r) - interB);       \
            ibB_##r = __float_as_uint(iouB);                       \
            unsigned long long ktA =                               \
                ((unsigned long long)ibA_##r << 32) | naiA;        \
            unsigned long long ktB =                               \
                ((unsigned long long)ibB_##r << 32) | naiB;        \
            unsigned long long kmx = (ktA > ktB) ? ktA : ktB;      \
            unsigned long long kmn = (ktA > ktB) ? ktB : ktA;      \
            if (kmn > t2_##r) {                                    \
                INS3(t0_##r, t1_##r, t2_##r, kmx);                 \
                INS3(t0_##r, t1_##r, t2_##r, kmn);                 \
            } else {                                               \
                INS3(t0_##r, t1_##r, t2_##r, kmx);                 \
            } }
            PAIR2(0) PAIR2(1) PAIR2(2) PAIR2(3)

            // per-lane max iou bits over 4 slots, then u32 wave butterfly
            unsigned mxA = max(max(ibA_0, ibA_1), max(ibA_2, ibA_3));
            unsigned mxB = max(max(ibB_0, ibB_1), max(ibB_2, ibB_3));
            for (int off = 1; off < 64; off <<= 1) {
                unsigned oA = __shfl_xor(mxA, off, 64);
                unsigned oB = __shfl_xor(mxB, off, 64);
                mxA = (oA > mxA) ? oA : mxA;
                mxB = (oB > mxB) ? oB : mxB;
            }

            // argmax index: smallest m = smallest slot r, then smallest lane
            unsigned long long bA0 = __ballot(ibA_0 == mxA);
            unsigned long long bA1 = __ballot(ibA_1 == mxA);
            unsigned long long bA2 = __ballot(ibA_2 == mxA);
            unsigned long long bA3 = __ballot(ibA_3 == mxA);
            int mA;
            if      (bA0) mA =       __builtin_ctzll(bA0);
            else if (bA1) mA =  64 + __builtin_ctzll(bA1);
            else if (bA2) mA = 128 + __builtin_ctzll(bA2);
            else          mA = 192 + __builtin_ctzll(bA3);

            unsigned long long bB0 = __ballot(ibB_0 == mxB);
            unsigned long long bB1 = __ballot(ibB_1 == mxB);
            unsigned long long bB2 = __ballot(ibB_2 == mxB);
            unsigned long long bB3 = __ballot(ibB_3 == mxB);
            int mB;
            if      (bB0) mB =       __builtin_ctzll(bB0);
            else if (bB1) mB =  64 + __builtin_ctzll(bB1);
            else if (bB2) mB = 128 + __builtin_ctzll(bB2);
            else          mB = 192 + __builtin_ctzll(bB3);

            // thresholds as unsigned bit-compares (iou >= 0 -> monotone)
            int vA = -2;
            if (mxA < __float_as_uint(NEG_THRESH)) vA = -1;
            if (mxA > __float_as_uint(POS_THRESH)) vA = mA;
            int vB = -2;
            if (mxB < __float_as_uint(NEG_THRESH)) vB = -1;
            if (mxB > __float_as_uint(POS_THRESH)) vB = mB;
            if (jj == lane)     myassign = vA;
            if (jj + 1 == lane) myassign = vB;
        }

        int gout = jbase + lane;
        if (gout < N) out[gout] = myassign;
    }

    // ---- merge 4 waves' per-GT top-3, one slot r at a time (6 KB LDS) ---
    const int blk = blockIdx.x;
#define EPI(r) {                                                   \
    __syncthreads();                                               \
    s_red[w][lane][0] = t0_##r;                                    \
    s_red[w][lane][1] = t1_##r;                                    \
    s_red[w][lane][2] = t2_##r;                                    \
    __syncthreads();                                               \
    if (tid < 64) {                                                \
        int m = tid + (r) * 64;                                    \
        if (m < M) {                                               \
            unsigned long long r0 = 0, r1 = 0, r2 = 0;             \
            for (int wv = 0; wv < 4; ++wv) {                       \
                INS3(r0, r1, r2, s_red[wv][tid][0]);               \
                INS3(r0, r1, r2, s_red[wv][tid][1]);               \
                INS3(r0, r1, r2, s_red[wv][tid][2]);               \
            }                                                      \
            partial[((size_t)blk * 3 + 0) * M + m] = r0;           \
            partial[((size_t)blk * 3 + 1) * M + m] = r1;           \
            partial[((size_t)blk * 3 + 2) * M + m] = r2;           \
        }                                                          \
    } }
    EPI(0) EPI(1) EPI(2) EPI(3)
}

// ---------------------------------------------------------------------------
// Mid-stage reduce: G2 blocks x 256 threads, LANES ON m (coalesced reads).
// Block b merges its chunk range into mid[(b*3+k)*M + m].
// ---------------------------------------------------------------------------
__global__ void __launch_bounds__(256) k_mid(
    const unsigned long long* __restrict__ partial,
    unsigned long long* __restrict__ mid, int M, int nblk)
{
    const int m = threadIdx.x;
    const int b = blockIdx.x;
    const int per = (nblk + G2 - 1) / G2;
    const int c0 = b * per;
    const int c1 = (c0 + per < nblk) ? c0 + per : nblk;

    if (m < M) {
        unsigned long long r0 = 0, r1 = 0, r2 = 0;
        for (int c = c0; c < c1; ++c) {
            const unsigned long long* p = partial + (size_t)c * 3 * M + m;
            INS3(r0, r1, r2, p[0 * M]);     // coalesced across lanes
            INS3(r0, r1, r2, p[1 * M]);
            INS3(r0, r1, r2, p[2 * M]);
        }
        mid[((size_t)b * 3 + 0) * M + m] = r0;
        mid[((size_t)b * 3 + 1) * M + m] = r1;
        mid[((size_t)b * 3 + 2) * M + m] = r2;
    }
}

// ---------------------------------------------------------------------------
// Per-GT reduce: grid = M blocks; thread tid merges mid chunk tid, butterfly.
// ---------------------------------------------------------------------------
__global__ void __launch_bounds__(256) k_gt(
    const unsigned long long* __restrict__ mid,
    unsigned long long* __restrict__ final3, int M)
{
    const int m    = blockIdx.x;
    const int tid  = threadIdx.x;
    const int lane = tid & 63;
    const int w    = tid >> 6;

    unsigned long long r0 = 0, r1 = 0, r2 = 0;
    {
        const unsigned long long* p = mid + (size_t)tid * 3 * M + m;
        INS3(r0, r1, r2, p[0 * M]);
        INS3(r0, r1, r2, p[1 * M]);
        INS3(r0, r1, r2, p[2 * M]);
    }

    for (int off = 1; off < 64; off <<= 1) {
        unsigned long long o0 = shfl_xor_u64(r0, off);
        unsigned long long o1 = shfl_xor_u64(r1, off);
        unsigned long long o2 = shfl_xor_u64(r2, off);
        INS3(r0, r1, r2, o0);
        INS3(r0, r1, r2, o1);
        INS3(r0, r1, r2, o2);
    }

    __shared__ unsigned long long s_red[4][3];
    if (lane == 0) {
        s_red[w][0] = r0; s_red[w][1] = r1; s_red[w][2] = r2;
    }
    __syncthreads();
    if (tid == 0) {
        unsigned long long q0 = 0, q1 = 0, q2 = 0;
        for (int wv = 0; wv < 4; ++wv) {
            INS3(q0, q1, q2, s_red[wv][0]);
            INS3(q0, q1, q2, s_red[wv][1]);
            INS3(q0, q1, q2, s_red[wv][2]);
        }
        final3[m * 3 + 0] = q0;
        final3[m * 3 + 1] = q1;
        final3[m * 3 + 2] = q2;
    }
}

// ---------------------------------------------------------------------------
// Claims: apply forced-claim scatter-max. Single block, BREAK-FREE winner
// check over packed keys: claim key = ((u64)anchor << 32) | gt_idx.
// Claim e wins iff key[e] == max{ key[f] : anchor[f] == anchor[e] }.
// (keys with the same anchor are distinct since gt indices are distinct)
// ---------------------------------------------------------------------------
__global__ void __launch_bounds__(256) k_claims(
    const unsigned long long* __restrict__ final3, int* __restrict__ out, int M)
{
    __shared__ unsigned long long s_key[3 * MPAD];
    const int tid = threadIdx.x;

    if (tid < M) {
        unsigned long long q0 = final3[tid * 3 + 0];
        unsigned long long q1 = final3[tid * 3 + 1];
        unsigned long long q2 = final3[tid * 3 + 2];
        float v1 = __uint_as_float((unsigned)(q1 >> 32));
        float v2 = __uint_as_float((unsigned)(q2 >> 32));
        unsigned a0 = ~(unsigned)q0;
        unsigned a1 = ~(unsigned)q1;
        unsigned a2 = ~(unsigned)q2;

        float v0 = __uint_as_float((unsigned)(q0 >> 32));
        int npos = (v0 > POS_THRESH) + (v1 > POS_THRESH) + (v2 > POS_THRESH);
        bool low = npos < 3;

        // invalid claims get key 0: can never displace a genuine claim
        // (genuine keys have nonzero anchor-or-gt bits and win the max)
        s_key[tid * 3 + 0] = ((unsigned long long)a0 << 32) | (unsigned)tid;
        s_key[tid * 3 + 1] = (low && v1 > CLAIM_THRESH)
            ? (((unsigned long long)a1 << 32) | (unsigned)tid) : 0ULL;
        s_key[tid * 3 + 2] = (low && v2 > CLAIM_THRESH)
            ? (((unsigned long long)a2 << 32) | (unsigned)tid) : 0ULL;
    }
    __syncthreads();

    const int tote = 3 * M;
    for (int e = tid; e < tote; e += 256) {
        unsigned long long my = s_key[e];
        if ((my & 0xffffffffULL) == 0 && my == 0) continue;   // invalid slot
        unsigned myA = (unsigned)(my >> 32);
        unsigned long long mx = 0;
        for (int f = 0; f < tote; ++f) {          // break-free: pipelineable
            unsigned long long k = s_key[f];
            bool same = (unsigned)(k >> 32) == myA;
            if (same && k > mx) mx = k;
        }
        if (mx == my) out[myA] = (int)(my & 0xffffffffULL);
    }
}

// ---------------------------------------------------------------------------
extern "C" void kernel_launch(void* const* d_in, const int* in_sizes, int n_in,
                              void* d_out, int out_size, void* d_ws, size_t ws_size,
                              hipStream_t stream) {
    const float4* anchor = (const float4*)d_in[0];
    const float4* gt     = (const float4*)d_in[1];
    int N = in_sizes[0] / 4;
    int M = in_sizes[1] / 4;
    int* out = (int*)d_out;

    // slice = anchors per block (multiple of 256); fall back to bigger slices
    // if the partial buffer would overflow the workspace.
    int slice = 256;
    int nblk  = (N + slice - 1) / slice;
    while ((size_t)(nblk * 3 + G2 * 3 + 3) * M * sizeof(unsigned long long) >
               ws_size && slice < (1 << 24)) {
        slice <<= 1;
        nblk = (N + slice - 1) / slice;
    }

    unsigned long long* partial = (unsigned long long*)d_ws;
    unsigned long long* mid     = partial + (size_t)nblk * 3 * M;
    unsigned long long* final3  = mid + (size_t)G2 * 3 * M;

    k_fused<<<nblk, 256, 0, stream>>>(anchor, gt, out, partial, N, M, slice);
    k_mid<<<G2, 256, 0, stream>>>(partial, mid, M, nblk);
    k_gt<<<M, 256, 0, stream>>>(mid, final3, M);
    k_claims<<<1, 256, 0, stream>>>(final3, out, M);
}